// Round 2
// baseline (673.519 us; speedup 1.0000x reference)
//
#include <hip/hip_runtime.h>

#define NODES_PER_BLOCK 64

__global__ void zero_kernel(float* __restrict__ p, int total) {
  int i = blockIdx.x * blockDim.x + threadIdx.x;
  if (i < total) p[i] = 0.0f;
}

// deg[v] = 1 (self loop)
__global__ void init_deg_kernel(float* __restrict__ deg, int n) {
  int i = blockIdx.x * blockDim.x + threadIdx.x;
  if (i < n) deg[i] = 1.0f;
}

// deg[col[e]] += 1   (edge_index is int32 — JAX x64 is off)
__global__ void count_kernel(const int* __restrict__ col, float* __restrict__ deg, int e) {
  int i = blockIdx.x * blockDim.x + threadIdx.x;
  if (i < e) atomicAdd(deg + col[i], 1.0f);
}

__global__ void dinv_kernel(const float* __restrict__ deg, float* __restrict__ dinv, int n) {
  int i = blockIdx.x * blockDim.x + threadIdx.x;
  if (i < n) dinv[i] = rsqrtf(deg[i]);
}

// s1 = (x @ W1) * dinv ; x [n,128] f32, W1 [128,16]
__global__ __launch_bounds__(256) void mm1_kernel(const float* __restrict__ x,
                                                  const float* __restrict__ W1,
                                                  const float* __restrict__ dinv,
                                                  float* __restrict__ s1, int n) {
  __shared__ float xs[NODES_PER_BLOCK][129];  // +1 pad: breaks 16-way bank conflict
  __shared__ float ws[128 * 16];
  int t = threadIdx.x;
  for (int i = t; i < 128 * 16; i += 256) ws[i] = W1[i];
  int base = blockIdx.x * NODES_PER_BLOCK;
  for (int i = t * 4; i < NODES_PER_BLOCK * 128; i += 256 * 4) {
    int nn = i >> 7, k = i & 127;
    if (base + nn < n) {
      float4 v = *(const float4*)(x + (size_t)(base + nn) * 128 + k);
      xs[nn][k] = v.x; xs[nn][k + 1] = v.y; xs[nn][k + 2] = v.z; xs[nn][k + 3] = v.w;
    }
  }
  __syncthreads();
  int nn = t >> 2;            // 4 threads per node
  int j0 = (t & 3) * 4;       // 4 consecutive outputs each
  float a0 = 0, a1 = 0, a2 = 0, a3 = 0;
  #pragma unroll 8
  for (int k = 0; k < 128; k++) {
    float xv = xs[nn][k];
    const float* wr = ws + k * 16 + j0;
    a0 += xv * wr[0]; a1 += xv * wr[1]; a2 += xv * wr[2]; a3 += xv * wr[3];
  }
  int node = base + nn;
  if (node < n) {
    float d = dinv[node];
    float4 o; o.x = a0 * d; o.y = a1 * d; o.z = a2 * d; o.w = a3 * d;
    *(float4*)(s1 + (size_t)node * 16 + j0) = o;
  }
}

// 16 lanes per edge: acc[col[e]*16+f] += s[row[e]*16+f]
__global__ void scatter_kernel(const int* __restrict__ row, const int* __restrict__ col,
                               const float* __restrict__ s, float* __restrict__ acc, int e) {
  int t = blockIdx.x * blockDim.x + threadIdx.x;
  int total = e * 16;
  if (t < total) {
    int eidx = t >> 4, f = t & 15;
    int r = row[eidx];
    int c = col[eidx];
    atomicAdd(acc + (size_t)c * 16 + f, s[(size_t)r * 16 + f]);
  }
}

// s <- relu(dinv*(acc+s) + b1) * dinv   (in place; prepares layer-2 pre-scaled input)
__global__ void post1_kernel(float* __restrict__ s, const float* __restrict__ acc,
                             const float* __restrict__ dinv, const float* __restrict__ b1,
                             int total) {
  int t = blockIdx.x * blockDim.x + threadIdx.x;
  if (t < total) {
    int v = t >> 4, j = t & 15;
    float d = dinv[v];
    float h = fmaf(d, acc[t] + s[t], b1[j]);
    h = fmaxf(h, 0.0f);
    s[t] = h * d;
  }
}

// out[v][j] = sum_k (dinv[v]*(acc[v,k]+s[v,k])) * W2[k][j] + b2[j]
__global__ __launch_bounds__(256) void final_kernel(const float* __restrict__ s,
                                                    const float* __restrict__ acc,
                                                    const float* __restrict__ dinv,
                                                    const float* __restrict__ W2,
                                                    const float* __restrict__ b2,
                                                    float* __restrict__ out, int n) {
  __shared__ float w2s[16 * 64];
  __shared__ float b2s[64];
  int t = threadIdx.x;
  for (int i = t; i < 16 * 64; i += 256) w2s[i] = W2[i];
  if (t < 64) b2s[t] = b2[t];
  __syncthreads();
  int node = blockIdx.x * 4 + (t >> 6);
  int j = t & 63;
  if (node < n) {
    float d = dinv[node];
    const float* sp = s + (size_t)node * 16;
    const float* ap = acc + (size_t)node * 16;
    float o = b2s[j];
    #pragma unroll
    for (int k = 0; k < 16; k++) {
      float a = d * (ap[k] + sp[k]);
      o = fmaf(a, w2s[k * 64 + j], o);
    }
    out[(size_t)node * 64 + j] = o;
  }
}

extern "C" void kernel_launch(void* const* d_in, const int* in_sizes, int n_in,
                              void* d_out, int out_size, void* d_ws, size_t ws_size,
                              hipStream_t stream) {
  const float* x = (const float*)d_in[0];
  const int* ei = (const int*)d_in[1];   // int32! JAX x64 disabled
  const float* W1 = (const float*)d_in[2];
  const float* b1 = (const float*)d_in[3];
  const float* W2 = (const float*)d_in[4];
  const float* b2 = (const float*)d_in[5];
  float* out = (float*)d_out;

  int n = in_sizes[0] / 128;   // 100000
  int e = in_sizes[1] / 2;     // 3200000
  const int* row = ei;         // sources
  const int* col = ei + e;     // targets

  float* wsf = (float*)d_ws;
  size_t nA = (((size_t)n) + 63) & ~(size_t)63;
  float* deg = wsf;
  float* dinv = wsf + nA;
  float* s = wsf + 2 * nA;                 // [n,16] pre-scaled node features
  float* acc = s + (size_t)n * 16;         // [n,16] aggregation accumulator

  init_deg_kernel<<<(n + 255) / 256, 256, 0, stream>>>(deg, n);
  count_kernel<<<(e + 255) / 256, 256, 0, stream>>>(col, deg, e);
  dinv_kernel<<<(n + 255) / 256, 256, 0, stream>>>(deg, dinv, n);

  // layer 1: transform first (128 -> 16), then aggregate 16-wide
  mm1_kernel<<<(n + NODES_PER_BLOCK - 1) / NODES_PER_BLOCK, 256, 0, stream>>>(x, W1, dinv, s, n);
  zero_kernel<<<(n * 16 + 255) / 256, 256, 0, stream>>>(acc, n * 16);
  scatter_kernel<<<(e * 16 + 255) / 256, 256, 0, stream>>>(row, col, s, acc, e);
  post1_kernel<<<(n * 16 + 255) / 256, 256, 0, stream>>>(s, acc, dinv, b1, n * 16);

  // layer 2: aggregate FIRST (16-wide), then transform (16 -> 64) — reassociated vs reference
  zero_kernel<<<(n * 16 + 255) / 256, 256, 0, stream>>>(acc, n * 16);
  scatter_kernel<<<(e * 16 + 255) / 256, 256, 0, stream>>>(row, col, s, acc, e);
  final_kernel<<<(n + 3) / 4, 256, 0, stream>>>(s, acc, dinv, W2, b2, out, n);
}